// Round 4
// baseline (348.406 us; speedup 1.0000x reference)
//
#include <hip/hip_runtime.h>

// B=2, T=2048, C=2048, H=16, KH=4, D=128, rep=4

typedef __attribute__((ext_vector_type(8))) short bf16x8;
typedef __attribute__((ext_vector_type(4))) short bf16x4;
typedef __attribute__((ext_vector_type(4))) float f32x4;

__device__ __forceinline__ unsigned short f2bf(float f) {
  union { float f; unsigned u; } v; v.f = f;
  unsigned u = v.u;
  u += 0x7fffu + ((u >> 16) & 1u);   // RNE
  return (unsigned short)(u >> 16);
}
__device__ __forceinline__ float bf2f(unsigned short h) {
  union { unsigned u; float f; } v; v.u = ((unsigned)h) << 16;
  return v.f;
}
__device__ __forceinline__ unsigned cvtpk_bf16(float lo, float hi) {
  unsigned r;
  asm("v_cvt_pk_bf16_f32 %0, %1, %2" : "=v"(r) : "v"(lo), "v"(hi));
  return r;  // low16 = bf16(lo), high16 = bf16(hi)
}

// global -> LDS async copy, 16B per lane. LDS dest must be wave-uniform;
// HW writes lane l at dest + 16*l. Source addr is per-lane.
__device__ __forceinline__ void gl_lds16(const void* g, void* l) {
  __builtin_amdgcn_global_load_lds(
      (const __attribute__((address_space(1))) unsigned int*)(unsigned long long)g,
      (__attribute__((address_space(3))) unsigned int*)(unsigned int)(unsigned long long)l,
      16, 0, 0);
}

// ---------------------------------------------------------------------------
// fp32 -> bf16 cast, 4-wide
__global__ void cvt_f32_bf16(const float* __restrict__ src,
                             unsigned short* __restrict__ dst, long n4) {
  long i = (long)blockIdx.x * blockDim.x + threadIdx.x;
  const long stride = (long)gridDim.x * blockDim.x;
  for (; i < n4; i += stride) {
    const float4 vv = ((const float4*)src)[i];
    ushort4 o;
    o.x = f2bf(vv.x); o.y = f2bf(vv.y); o.z = f2bf(vv.z); o.w = f2bf(vv.w);
    ((ushort4*)dst)[i] = o;
  }
}

// Wq|Wk|Wv -> concatenated bf16 (3072 x 2048), one launch
__global__ void cvt_w3(const float* __restrict__ wq, const float* __restrict__ wk,
                       const float* __restrict__ wv, unsigned short* __restrict__ dst) {
  const long n4q = (long)2048 * 2048 / 4, n4k = (long)512 * 2048 / 4;
  const long tot = n4q + 2 * n4k;
  long i = (long)blockIdx.x * blockDim.x + threadIdx.x;
  const long stride = (long)gridDim.x * blockDim.x;
  for (; i < tot; i += stride) {
    const float4 vv = (i < n4q) ? ((const float4*)wq)[i]
                    : (i < n4q + n4k) ? ((const float4*)wk)[i - n4q]
                    : ((const float4*)wv)[i - n4q - n4k];
    ushort4 o;
    o.x = f2bf(vv.x); o.y = f2bf(vv.y); o.z = f2bf(vv.z); o.w = f2bf(vv.w);
    ((ushort4*)dst)[i] = o;
  }
}

// ---------------------------------------------------------------------------
// 256x256 8-phase NT GEMM (m201-style): C[M,N] = A[M,K]*B[N,K]^T, bf16 in.
#define PHASE(QM, QN, PF, GATE)                                               \
  {                                                                           \
    bf16x8 af[4][2], bg[2][2];                                                \
    _Pragma("unroll") for (int r = 0; r < 4; ++r) {                           \
      const char* pa = ldsc + curb + (((QM)*128 + arow0 + r*16) << 7);        \
      af[r][0] = *(const bf16x8*)(pa + csw0);                                 \
      af[r][1] = *(const bf16x8*)(pa + csw1);                                 \
    }                                                                         \
    _Pragma("unroll") for (int n = 0; n < 2; ++n) {                           \
      const char* pb = ldsc + curb + 32768 + (((QN)*128 + brow0 + n*16) << 7);\
      bg[n][0] = *(const bf16x8*)(pb + csw0);                                 \
      bg[n][1] = *(const bf16x8*)(pb + csw1);                                 \
    }                                                                         \
    PF                                                                        \
    __builtin_amdgcn_s_barrier();                                             \
    asm volatile("s_waitcnt lgkmcnt(0)" ::: "memory");                        \
    __builtin_amdgcn_sched_barrier(0);                                        \
    __builtin_amdgcn_s_setprio(1);                                            \
    _Pragma("unroll") for (int r = 0; r < 4; ++r)                             \
      _Pragma("unroll") for (int n = 0; n < 2; ++n) {                         \
        acc[(QM)*4+r][(QN)*2+n] = __builtin_amdgcn_mfma_f32_16x16x32_bf16(    \
            af[r][0], bg[n][0], acc[(QM)*4+r][(QN)*2+n], 0, 0, 0);            \
        acc[(QM)*4+r][(QN)*2+n] = __builtin_amdgcn_mfma_f32_16x16x32_bf16(    \
            af[r][1], bg[n][1], acc[(QM)*4+r][(QN)*2+n], 0, 0, 0);            \
      }                                                                       \
    __builtin_amdgcn_s_setprio(0);                                            \
    GATE                                                                      \
    __builtin_amdgcn_s_barrier();                                             \
  }

template <int OUT_BF16>
__global__ __launch_bounds__(512, 2)
void gemm256(const unsigned short* __restrict__ A,
             const unsigned short* __restrict__ Bm,
             void* __restrict__ Cp, int M, int N, int K) {
  __shared__ __align__(16) char ldsc[131072];  // [2 buf][A 32KB | B 32KB]
  const int nbn = N >> 8;
  int wg = blockIdx.x;
  { // XCD swizzle; grids are multiples of 8 -> bijective
    const int cpx = (int)gridDim.x >> 3;
    wg = (wg & 7) * cpx + (wg >> 3);
  }
  const int m0 = (wg / nbn) << 8, n0 = (wg % nbn) << 8;
  const int tid = threadIdx.x;
  const int lane = tid & 63, wid = tid >> 6;
  const int lr = lane & 15, lg = lane >> 4;
  const int wm = wid >> 2, wn = wid & 3;  // 2 x 4 wave grid
  const int csw0 = (lg << 4) ^ ((lr & 7) << 4);
  const int csw1 = (64 + (lg << 4)) ^ ((lr & 7) << 4);
  const int arow0 = (wm << 6) + lr;
  const int brow0 = (wn << 5) + lr;
  const int srowL = tid >> 3;  // 0..63
  const int scol = ((tid & 7) ^ (srowL & 7)) << 3;
  const unsigned short* Asrc = A + (size_t)(m0 + srowL) * K + scol;
  const unsigned short* Bsrc = Bm + (size_t)(n0 + srowL) * K + scol;
  const int sdst = wid << 10;
  const int NT = K >> 6;
  f32x4 acc[8][4] = {};
  gl_lds16(Asrc, ldsc + sdst);
  gl_lds16(Asrc + (size_t)64 * K, ldsc + 8192 + sdst);
  gl_lds16(Bsrc, ldsc + 32768 + sdst);
  gl_lds16(Bsrc + (size_t)64 * K, ldsc + 40960 + sdst);
  gl_lds16(Asrc + (size_t)128 * K, ldsc + 16384 + sdst);
  gl_lds16(Asrc + (size_t)192 * K, ldsc + 24576 + sdst);
  gl_lds16(Bsrc + (size_t)128 * K, ldsc + 49152 + sdst);
  gl_lds16(Bsrc + (size_t)192 * K, ldsc + 57344 + sdst);
  asm volatile("s_waitcnt vmcnt(4)" ::: "memory");
  __builtin_amdgcn_s_barrier();

  for (int t = 0; t < NT; ++t) {
    const int curb = (t & 1) << 16;
    const int nxtb = curb ^ 65536;
    const size_t kn = (size_t)(t + 1) << 6;
    const bool pf = (t + 1) < NT;
    PHASE(0, 0,
      if (pf) { gl_lds16(Asrc + kn, ldsc + nxtb + sdst);
                gl_lds16(Asrc + (size_t)64 * K + kn, ldsc + nxtb + 8192 + sdst); },
      if (pf) { asm volatile("s_waitcnt vmcnt(2)" ::: "memory"); }
      else    { asm volatile("s_waitcnt vmcnt(0)" ::: "memory"); } )
    PHASE(1, 0,
      if (pf) { gl_lds16(Bsrc + kn, ldsc + nxtb + 32768 + sdst);
                gl_lds16(Bsrc + (size_t)64 * K + kn, ldsc + nxtb + 40960 + sdst); }, )
    PHASE(0, 1,
      if (pf) { gl_lds16(Asrc + (size_t)128 * K + kn, ldsc + nxtb + 16384 + sdst);
                gl_lds16(Asrc + (size_t)192 * K + kn, ldsc + nxtb + 24576 + sdst); }, )
    PHASE(1, 1,
      if (pf) { gl_lds16(Bsrc + (size_t)128 * K + kn, ldsc + nxtb + 49152 + sdst);
                gl_lds16(Bsrc + (size_t)192 * K + kn, ldsc + nxtb + 57344 + sdst); },
      if (pf) { asm volatile("s_waitcnt vmcnt(4)" ::: "memory"); } )
  }
  #pragma unroll
  for (int mi = 0; mi < 8; ++mi) {
    const int mrow = m0 + ((mi >> 2) << 7) + (wm << 6) + ((mi & 3) << 4) + (lg << 2);
    #pragma unroll
    for (int ni = 0; ni < 4; ++ni) {
      const int ncol = n0 + ((ni >> 1) << 7) + (wn << 5) + ((ni & 1) << 4) + lr;
      #pragma unroll
      for (int i = 0; i < 4; ++i) {
        if constexpr (OUT_BF16)
          ((unsigned short*)Cp)[(size_t)(mrow + i) * N + ncol] = f2bf(acc[mi][ni][i]);
        else
          ((float*)Cp)[(size_t)(mrow + i) * N + ncol] = acc[mi][ni][i];
      }
    }
  }
}

// ---------------------------------------------------------------------------
// RMSNorm + RoPE, wave-per-row, vectorized. Q pre-scaled by 1/sqrt(D).
__global__ __launch_bounds__(256)
void norm_rope(const unsigned short* __restrict__ qkv,  // (B*T, 3072) bf16
               const float* __restrict__ cosb, const float* __restrict__ sinb,
               const float* __restrict__ qw, const float* __restrict__ kw,
               unsigned short* __restrict__ Qb,   // (B,H,T,D)
               unsigned short* __restrict__ Kb) { // (B,KH,T,D)
  const int wv = threadIdx.x >> 6, l = threadIdx.x & 63;
  const int rr = blockIdx.x * 4 + wv;
  const int hh = rr % 20, bt = rr / 20;
  const bool isq = hh < 16;
  const ushort2 u = *(const ushort2*)(qkv + (size_t)bt * 3072 + (hh << 7) + 2 * l);
  const float v0 = bf2f(u.x), v1 = bf2f(u.y);
  float ss = v0 * v0 + v1 * v1;
  #pragma unroll
  for (int off = 1; off < 64; off <<= 1) ss += __shfl_xor(ss, off);
  const float rms = rsqrtf(ss * (1.0f / 128.0f) + 1e-6f);
  const float* w = isq ? qw : kw;
  const float2 w2 = *(const float2*)(w + 2 * l);
  const float n0 = v0 * rms * w2.x, n1 = v1 * rms * w2.y;
  const float sx0 = __shfl_xor(n0, 32), sx1 = __shfl_xor(n1, 32);
  const float p0 = (l < 32) ? -sx0 : sx0;
  const float p1 = (l < 32) ? -sx1 : sx1;
  const float2 c2 = *(const float2*)(cosb + (size_t)bt * 128 + 2 * l);
  const float2 s2 = *(const float2*)(sinb + (size_t)bt * 128 + 2 * l);
  const float qsc = isq ? 0.08838834764831845f : 1.0f;  // 1/sqrt(128) folded into Q
  ushort2 o;
  o.x = f2bf((n0 * c2.x + p0 * s2.x) * qsc);
  o.y = f2bf((n1 * c2.y + p1 * s2.y) * qsc);
  const int b = bt >> 11, t = bt & 2047;
  if (isq)
    *(ushort2*)(Qb + (((size_t)(b * 16 + hh) * 2048 + t) << 7) + 2 * l) = o;
  else
    *(ushort2*)(Kb + (((size_t)(b * 4 + (hh - 16)) * 2048 + t) << 7) + 2 * l) = o;
}

// ---------------------------------------------------------------------------
// V transpose+cast: qkv v-columns (B,T,KH,D) -> Vt (B,KH,D,T) bf16
__global__ __launch_bounds__(256)
void v_trans(const unsigned short* __restrict__ qkv, unsigned short* __restrict__ Vt) {
  __shared__ unsigned short tile[64][66];
  const int b = blockIdx.x >> 2, h = blockIdx.x & 3;
  const int t0 = blockIdx.y << 6, d0 = blockIdx.z << 6;
  const int tid = threadIdx.x;
  #pragma unroll
  for (int p = 0; p < 16; ++p) {
    const int id = (p << 8) + tid;
    const int r = id >> 6, c = id & 63;  // r = t, c = d
    tile[r][c] = qkv[(size_t)(b * 2048 + t0 + r) * 3072 + 2560 + (h << 7) + d0 + c];
  }
  __syncthreads();
  #pragma unroll
  for (int p = 0; p < 16; ++p) {
    const int id = (p << 8) + tid;
    const int r = id >> 6, c = id & 63;  // r = d, c = t
    Vt[(size_t)((b * 4 + h) * 128 + d0 + r) * 2048 + t0 + c] = tile[c][r];
  }
}

// ---------------------------------------------------------------------------
// Causal GQA flash attention, paired q-tiles, SWAPPED QK^T (S^T = K*Q^T) so
// each lane owns one q-row: softmax is in-lane + 2 shfls; P packed in-reg
// via v_cvt_pk_bf16_f32; PV uses a PERMUTED contraction order so packed P
// words are lane-local (no exchange). Defer-max (THR=8). LDS 32KB.
__global__ __launch_bounds__(256, 4)
void attn_fwd(const unsigned short* __restrict__ Qb,  // (B,H,T,D), pre-scaled
              const unsigned short* __restrict__ Kb,  // (B,KH,T,D)
              const unsigned short* __restrict__ Vt,  // (B,KH,D,T)
              unsigned short* __restrict__ Y) {       // (B,T,H,D)
  __shared__ unsigned short Ks[64 * 128];   // 16KB, rows 256B, XOR-swizzled
  __shared__ unsigned short Vs[128 * 64];   // 16KB, rows 128B, XOR-swizzled
  const int bh = blockIdx.x;
  const int b = bh >> 4, h = bh & 15, hk = h >> 2;
  const int p = blockIdx.y;
  const int qtj[2] = {p, 31 - p};
  const int tid = threadIdx.x;
  const int lane = tid & 63, wv = tid >> 6;
  const int lr = lane & 15, lg = lane >> 4;
  const unsigned short* Kp = Kb + (size_t)(b * 4 + hk) * 2048 * 128;
  const unsigned short* Vp = Vt + (size_t)(b * 4 + hk) * 128 * 2048;
  bf16x8 aq[2][4];
  #pragma unroll
  for (int j = 0; j < 2; ++j) {
    const unsigned short* Qp =
        Qb + (size_t)((b * 16 + h) * 2048 + qtj[j] * 64 + wv * 16 + lr) * 128;
    #pragma unroll
    for (int ks = 0; ks < 4; ++ks)
      aq[j][ks] = *(const bf16x8*)(Qp + (ks << 5) + (lg << 3));
  }
  float m_i[2] = {-1e30f, -1e30f};   // per-lane: one q-row per lane
  float l_i[2] = {0.f, 0.f};
  f32x4 acc[2][8] = {};
  const int kr_in = (lane >> 4), kcb = (lane & 15) << 4;   // K chunk: 4 rows x 256B
  const int vr_in = (lane >> 3), vcb = (lane & 7) << 4;    // V chunk: 8 rows x 128B
  const int swb = (lr & 7) << 4;   // row&7 == lr&7 for all fragment rows used
  const int nkb = 32 - p;
  for (int kb = 0; kb < nkb; ++kb) {
    const int k0 = kb << 6;
    #pragma unroll
    for (int i = 0; i < 4; ++i) {
      const int c = (wv << 2) + i;
      { const int r = (c << 2) + kr_in;
        const int sw = kcb ^ ((r & 7) << 4);
        gl_lds16(Kp + (size_t)(k0 + r) * 128 + (sw >> 1), &Ks[c << 9]); }
      { const int r = (c << 3) + vr_in;
        const int sw = vcb ^ ((r & 7) << 4);
        gl_lds16(Vp + (size_t)r * 2048 + k0 + (sw >> 1), &Vs[c << 9]); }
    }
    __syncthreads();
    #pragma unroll
    for (int j = 0; j < 2; ++j) {
      if (kb > qtj[j]) continue;   // uniform; only j=0 can skip
      // S^T = K Q^T: lane holds S[q=lr][kv = 16nf + 4lg + reg]
      f32x4 s[4] = {};
      __builtin_amdgcn_s_setprio(1);
      #pragma unroll
      for (int nf = 0; nf < 4; ++nf) {
        const int row = (nf << 4) + lr;
        #pragma unroll
        for (int ks = 0; ks < 4; ++ks) {
          const bf16x8 bk = *(const bf16x8*)(
              (const char*)Ks + (row << 8) + (((ks << 6) + (lg << 4)) ^ swb));
          s[nf] = __builtin_amdgcn_mfma_f32_16x16x32_bf16(bk, aq[j][ks], s[nf], 0, 0, 0);
        }
      }
      __builtin_amdgcn_s_setprio(0);
      const int qrow = qtj[j] * 64 + wv * 16 + lr;
      if (kb == qtj[j]) {   // causal mask, diag block only
        const int base = qrow - k0 - (lg << 2);  // mask if 16nf + r > base
        #pragma unroll
        for (int nf = 0; nf < 4; ++nf)
          #pragma unroll
          for (int r = 0; r < 4; ++r)
            if (16 * nf + r > base) s[nf][r] = -1e30f;
      }
      // row max: in-lane 16 + 2 shfls
      float mx = s[0][0];
      #pragma unroll
      for (int nf = 0; nf < 4; ++nf)
        #pragma unroll
        for (int r = 0; r < 4; ++r) mx = fmaxf(mx, s[nf][r]);
      mx = fmaxf(mx, __shfl_xor(mx, 16));
      mx = fmaxf(mx, __shfl_xor(mx, 32));
      // defer-max (THR=8)
      if (!__all(mx <= m_i[j] + 8.0f)) {
        const float mn = fmaxf(m_i[j], mx);
        const float r = __expf(m_i[j] - mn);
        m_i[j] = mn;
        l_i[j] *= r;
        #pragma unroll
        for (int df = 0; df < 8; ++df) {
          acc[j][df][0] *= r; acc[j][df][1] *= r;
          acc[j][df][2] *= r; acc[j][df][3] *= r;
        }
      }
      // P = exp(S - m), pack to bf16 pairs in-register
      float se = 0.f;
      unsigned pk[8];
      #pragma unroll
      for (int nf = 0; nf < 4; ++nf) {
        const float p0 = __expf(s[nf][0] - m_i[j]);
        const float p1 = __expf(s[nf][1] - m_i[j]);
        const float p2 = __expf(s[nf][2] - m_i[j]);
        const float p3 = __expf(s[nf][3] - m_i[j]);
        se += (p0 + p1) + (p2 + p3);
        pk[nf * 2] = cvtpk_bf16(p0, p1);
        pk[nf * 2 + 1] = cvtpk_bf16(p2, p3);
      }
      se += __shfl_xor(se, 16);
      se += __shfl_xor(se, 32);
      l_i[j] += se;
      // PV with permuted contraction: K-block c contracts
      // kv = 32c + 4lg + r (j=0..3) and 32c + 16 + 4lg + r (j=4..7)
      union { unsigned u[4]; bf16x8 v; } pb0, pb1;
      pb0.u[0] = pk[0]; pb0.u[1] = pk[1]; pb0.u[2] = pk[2]; pb0.u[3] = pk[3];
      pb1.u[0] = pk[4]; pb1.u[1] = pk[5]; pb1.u[2] = pk[6]; pb1.u[3] = pk[7];
      __builtin_amdgcn_s_setprio(1);
      #pragma unroll
      for (int df = 0; df < 8; ++df) {
        const char* vrow = (const char*)Vs + (((df << 4) + lr) << 7);
        union { bf16x4 h[2]; bf16x8 v; } va;
        va.h[0] = *(const bf16x4*)(vrow + (((lg << 3)) ^ swb));
        va.h[1] = *(const bf16x4*)(vrow + ((32 + (lg << 3)) ^ swb));
        acc[j][df] = __builtin_amdgcn_mfma_f32_16x16x32_bf16(va.v, pb0.v, acc[j][df], 0, 0, 0);
        va.h[0] = *(const bf16x4*)(vrow + ((64 + (lg << 3)) ^ swb));
        va.h[1] = *(const bf16x4*)(vrow + ((96 + (lg << 3)) ^ swb));
        acc[j][df] = __builtin_amdgcn_mfma_f32_16x16x32_bf16(va.v, pb1.v, acc[j][df], 0, 0, 0);
      }
      __builtin_amdgcn_s_setprio(0);
    }
    __syncthreads();
  }
  // epilogue: O^T layout -> lane has q=lr, d = 16df + 4lg + reg
  #pragma unroll
  for (int j = 0; j < 2; ++j) {
    const float inv = 1.0f / l_i[j];
    const int t = qtj[j] * 64 + wv * 16 + lr;
    unsigned short* Yp = Y + (((size_t)b * 2048 + t) * 16 + h) * 128 + (lg << 2);
    #pragma unroll
    for (int df = 0; df < 8; ++df) {
      ushort4 o;
      o.x = f2bf(acc[j][df][0] * inv);
      o.y = f2bf(acc[j][df][1] * inv);
      o.z = f2bf(acc[j][df][2] * inv);
      o.w = f2bf(acc[j][df][3] * inv);
      *(ushort4*)(Yp + (df << 4)) = o;
    }
  }
}

// ---------------------------------------------------------------------------
extern "C" void kernel_launch(void* const* d_in, const int* in_sizes, int n_in,
                              void* d_out, int out_size, void* d_ws, size_t ws_size,
                              hipStream_t stream) {
  const float* x    = (const float*)d_in[0];
  const float* cosb = (const float*)d_in[1];
  const float* sinb = (const float*)d_in[2];
  const float* Wq   = (const float*)d_in[3];
  const float* Wk   = (const float*)d_in[4];
  const float* Wv   = (const float*)d_in[5];
  const float* Wo   = (const float*)d_in[6];
  const float* qw   = (const float*)d_in[7];
  const float* kw   = (const float*)d_in[8];
  char* ws = (char*)d_ws;
  unsigned short* xb   = (unsigned short*)(ws);                       // 16MB x bf16, later reused as Y
  unsigned short* Wcat = (unsigned short*)(ws + (16ull << 20));       // 12MB [Wq;Wk;Wv] bf16
  unsigned short* Wob  = (unsigned short*)(ws + (28ull << 20));       // 8MB Wo bf16
  unsigned short* qkv  = (unsigned short*)(ws + (36ull << 20));       // 24MB (4096,3072) bf16
  unsigned short* Qb   = (unsigned short*)(ws + (60ull << 20));       // 16MB (B,H,T,D)
  unsigned short* Kb   = (unsigned short*)(ws + (76ull << 20));       // 4MB  (B,KH,T,D)
  unsigned short* Vt   = (unsigned short*)(ws + (80ull << 20));       // 4MB  (B,KH,D,T)

  cvt_f32_bf16<<<2048, 256, 0, stream>>>(x, xb, (long)(4096 * 2048 / 4));
  cvt_w3<<<1536, 256, 0, stream>>>(Wq, Wk, Wv, Wcat);
  cvt_f32_bf16<<<2048, 256, 0, stream>>>(Wo, Wob, (long)(2048 * 2048 / 4));

  // qkv = x @ [Wq;Wk;Wv]^T   (M=4096, N=3072, K=2048): 16x12 = 192 blocks
  gemm256<1><<<192, 512, 0, stream>>>(xb, Wcat, qkv, 4096, 3072, 2048);
  // RMSNorm + RoPE -> head-major Q (pre-scaled), K
  norm_rope<<<2 * 2048 * 20 / 4, 256, 0, stream>>>(qkv, cosb, sinb, qw, kw, Qb, Kb);
  // V -> transposed bf16
  v_trans<<<dim3(8, 32, 2), 256, 0, stream>>>(qkv, Vt);
  // attention -> Y (reuses xb); paired q-tiles
  attn_fwd<<<dim3(32, 16), 256, 0, stream>>>(Qb, Kb, Vt, xb);
  // out = Y @ Wo^T  (M=4096, N=2048, K=2048): 16x8 = 128 blocks, fp32 out
  gemm256<0><<<128, 512, 0, stream>>>(xb, Wob, d_out, 4096, 2048, 2048);
}

// Round 5
// 251.220 us; speedup vs baseline: 1.3869x; 1.3869x over previous
//
#include <hip/hip_runtime.h>

// B=2, T=2048, C=2048, H=16, KH=4, D=128, rep=4

typedef __attribute__((ext_vector_type(8))) short bf16x8;
typedef __attribute__((ext_vector_type(4))) short bf16x4;
typedef __attribute__((ext_vector_type(4))) float f32x4;

__device__ __forceinline__ unsigned short f2bf(float f) {
  union { float f; unsigned u; } v; v.f = f;
  unsigned u = v.u;
  u += 0x7fffu + ((u >> 16) & 1u);   // RNE
  return (unsigned short)(u >> 16);
}
__device__ __forceinline__ float bf2f(unsigned short h) {
  union { unsigned u; float f; } v; v.u = ((unsigned)h) << 16;
  return v.f;
}
__device__ __forceinline__ unsigned cvtpk_bf16(float lo, float hi) {
  unsigned r;
  asm("v_cvt_pk_bf16_f32 %0, %1, %2" : "=v"(r) : "v"(lo), "v"(hi));
  return r;  // low16 = bf16(lo), high16 = bf16(hi)
}

// global -> LDS async copy, 16B per lane. LDS dest must be wave-uniform;
// HW writes lane l at dest + 16*l. Source addr is per-lane.
__device__ __forceinline__ void gl_lds16(const void* g, void* l) {
  __builtin_amdgcn_global_load_lds(
      (const __attribute__((address_space(1))) unsigned int*)(unsigned long long)g,
      (__attribute__((address_space(3))) unsigned int*)(unsigned int)(unsigned long long)l,
      16, 0, 0);
}

// ---------------------------------------------------------------------------
// fp32 -> bf16 cast, 4-wide
__global__ void cvt_f32_bf16(const float* __restrict__ src,
                             unsigned short* __restrict__ dst, long n4) {
  long i = (long)blockIdx.x * blockDim.x + threadIdx.x;
  const long stride = (long)gridDim.x * blockDim.x;
  for (; i < n4; i += stride) {
    const float4 vv = ((const float4*)src)[i];
    ushort4 o;
    o.x = f2bf(vv.x); o.y = f2bf(vv.y); o.z = f2bf(vv.z); o.w = f2bf(vv.w);
    ((ushort4*)dst)[i] = o;
  }
}

// Wq|Wk|Wv -> concatenated bf16 (3072 x 2048), one launch
__global__ void cvt_w3(const float* __restrict__ wq, const float* __restrict__ wk,
                       const float* __restrict__ wv, unsigned short* __restrict__ dst) {
  const long n4q = (long)2048 * 2048 / 4, n4k = (long)512 * 2048 / 4;
  const long tot = n4q + 2 * n4k;
  long i = (long)blockIdx.x * blockDim.x + threadIdx.x;
  const long stride = (long)gridDim.x * blockDim.x;
  for (; i < tot; i += stride) {
    const float4 vv = (i < n4q) ? ((const float4*)wq)[i]
                    : (i < n4q + n4k) ? ((const float4*)wk)[i - n4q]
                    : ((const float4*)wv)[i - n4q - n4k];
    ushort4 o;
    o.x = f2bf(vv.x); o.y = f2bf(vv.y); o.z = f2bf(vv.z); o.w = f2bf(vv.w);
    ((ushort4*)dst)[i] = o;
  }
}

// ---------------------------------------------------------------------------
// 256x256 8-phase NT GEMM (m201-style): C[M,N] = A[M,K]*B[N,K]^T, bf16 in.
#define PHASE(QM, QN, PF, GATE)                                               \
  {                                                                           \
    bf16x8 af[4][2], bg[2][2];                                                \
    _Pragma("unroll") for (int r = 0; r < 4; ++r) {                           \
      const char* pa = ldsc + curb + (((QM)*128 + arow0 + r*16) << 7);        \
      af[r][0] = *(const bf16x8*)(pa + csw0);                                 \
      af[r][1] = *(const bf16x8*)(pa + csw1);                                 \
    }                                                                         \
    _Pragma("unroll") for (int n = 0; n < 2; ++n) {                           \
      const char* pb = ldsc + curb + 32768 + (((QN)*128 + brow0 + n*16) << 7);\
      bg[n][0] = *(const bf16x8*)(pb + csw0);                                 \
      bg[n][1] = *(const bf16x8*)(pb + csw1);                                 \
    }                                                                         \
    PF                                                                        \
    __builtin_amdgcn_s_barrier();                                             \
    asm volatile("s_waitcnt lgkmcnt(0)" ::: "memory");                        \
    __builtin_amdgcn_sched_barrier(0);                                        \
    __builtin_amdgcn_s_setprio(1);                                            \
    _Pragma("unroll") for (int r = 0; r < 4; ++r)                             \
      _Pragma("unroll") for (int n = 0; n < 2; ++n) {                         \
        acc[(QM)*4+r][(QN)*2+n] = __builtin_amdgcn_mfma_f32_16x16x32_bf16(    \
            af[r][0], bg[n][0], acc[(QM)*4+r][(QN)*2+n], 0, 0, 0);            \
        acc[(QM)*4+r][(QN)*2+n] = __builtin_amdgcn_mfma_f32_16x16x32_bf16(    \
            af[r][1], bg[n][1], acc[(QM)*4+r][(QN)*2+n], 0, 0, 0);            \
      }                                                                       \
    __builtin_amdgcn_s_setprio(0);                                            \
    GATE                                                                      \
    __builtin_amdgcn_s_barrier();                                             \
  }

template <int OUT_BF16>
__global__ __launch_bounds__(512, 2)
void gemm256(const unsigned short* __restrict__ A,
             const unsigned short* __restrict__ Bm,
             void* __restrict__ Cp, int M, int N, int K) {
  __shared__ __align__(16) char ldsc[131072];  // [2 buf][A 32KB | B 32KB]
  const int nbn = N >> 8;
  int wg = blockIdx.x;
  { // XCD swizzle; grids are multiples of 8 -> bijective
    const int cpx = (int)gridDim.x >> 3;
    wg = (wg & 7) * cpx + (wg >> 3);
  }
  const int m0 = (wg / nbn) << 8, n0 = (wg % nbn) << 8;
  const int tid = threadIdx.x;
  const int lane = tid & 63, wid = tid >> 6;
  const int lr = lane & 15, lg = lane >> 4;
  const int wm = wid >> 2, wn = wid & 3;  // 2 x 4 wave grid
  const int csw0 = (lg << 4) ^ ((lr & 7) << 4);
  const int csw1 = (64 + (lg << 4)) ^ ((lr & 7) << 4);
  const int arow0 = (wm << 6) + lr;
  const int brow0 = (wn << 5) + lr;
  const int srowL = tid >> 3;  // 0..63
  const int scol = ((tid & 7) ^ (srowL & 7)) << 3;
  const unsigned short* Asrc = A + (size_t)(m0 + srowL) * K + scol;
  const unsigned short* Bsrc = Bm + (size_t)(n0 + srowL) * K + scol;
  const int sdst = wid << 10;
  const int NT = K >> 6;
  f32x4 acc[8][4] = {};
  gl_lds16(Asrc, ldsc + sdst);
  gl_lds16(Asrc + (size_t)64 * K, ldsc + 8192 + sdst);
  gl_lds16(Bsrc, ldsc + 32768 + sdst);
  gl_lds16(Bsrc + (size_t)64 * K, ldsc + 40960 + sdst);
  gl_lds16(Asrc + (size_t)128 * K, ldsc + 16384 + sdst);
  gl_lds16(Asrc + (size_t)192 * K, ldsc + 24576 + sdst);
  gl_lds16(Bsrc + (size_t)128 * K, ldsc + 49152 + sdst);
  gl_lds16(Bsrc + (size_t)192 * K, ldsc + 57344 + sdst);
  asm volatile("s_waitcnt vmcnt(4)" ::: "memory");
  __builtin_amdgcn_s_barrier();

  for (int t = 0; t < NT; ++t) {
    const int curb = (t & 1) << 16;
    const int nxtb = curb ^ 65536;
    const size_t kn = (size_t)(t + 1) << 6;
    const bool pf = (t + 1) < NT;
    PHASE(0, 0,
      if (pf) { gl_lds16(Asrc + kn, ldsc + nxtb + sdst);
                gl_lds16(Asrc + (size_t)64 * K + kn, ldsc + nxtb + 8192 + sdst); },
      if (pf) { asm volatile("s_waitcnt vmcnt(2)" ::: "memory"); }
      else    { asm volatile("s_waitcnt vmcnt(0)" ::: "memory"); } )
    PHASE(1, 0,
      if (pf) { gl_lds16(Bsrc + kn, ldsc + nxtb + 32768 + sdst);
                gl_lds16(Bsrc + (size_t)64 * K + kn, ldsc + nxtb + 40960 + sdst); }, )
    PHASE(0, 1,
      if (pf) { gl_lds16(Asrc + (size_t)128 * K + kn, ldsc + nxtb + 16384 + sdst);
                gl_lds16(Asrc + (size_t)192 * K + kn, ldsc + nxtb + 24576 + sdst); }, )
    PHASE(1, 1,
      if (pf) { gl_lds16(Bsrc + (size_t)128 * K + kn, ldsc + nxtb + 49152 + sdst);
                gl_lds16(Bsrc + (size_t)192 * K + kn, ldsc + nxtb + 57344 + sdst); },
      if (pf) { asm volatile("s_waitcnt vmcnt(4)" ::: "memory"); } )
  }
  #pragma unroll
  for (int mi = 0; mi < 8; ++mi) {
    const int mrow = m0 + ((mi >> 2) << 7) + (wm << 6) + ((mi & 3) << 4) + (lg << 2);
    #pragma unroll
    for (int ni = 0; ni < 4; ++ni) {
      const int ncol = n0 + ((ni >> 1) << 7) + (wn << 5) + ((ni & 1) << 4) + lr;
      #pragma unroll
      for (int i = 0; i < 4; ++i) {
        if constexpr (OUT_BF16)
          ((unsigned short*)Cp)[(size_t)(mrow + i) * N + ncol] = f2bf(acc[mi][ni][i]);
        else
          ((float*)Cp)[(size_t)(mrow + i) * N + ncol] = acc[mi][ni][i];
      }
    }
  }
}

// ---------------------------------------------------------------------------
// RMSNorm + RoPE, wave-per-row, vectorized. Q pre-scaled by 1/sqrt(D).
__global__ __launch_bounds__(256)
void norm_rope(const unsigned short* __restrict__ qkv,  // (B*T, 3072) bf16
               const float* __restrict__ cosb, const float* __restrict__ sinb,
               const float* __restrict__ qw, const float* __restrict__ kw,
               unsigned short* __restrict__ Qb,   // (B,H,T,D)
               unsigned short* __restrict__ Kb) { // (B,KH,T,D)
  const int wv = threadIdx.x >> 6, l = threadIdx.x & 63;
  const int rr = blockIdx.x * 4 + wv;
  const int hh = rr % 20, bt = rr / 20;
  const bool isq = hh < 16;
  const ushort2 u = *(const ushort2*)(qkv + (size_t)bt * 3072 + (hh << 7) + 2 * l);
  const float v0 = bf2f(u.x), v1 = bf2f(u.y);
  float ss = v0 * v0 + v1 * v1;
  #pragma unroll
  for (int off = 1; off < 64; off <<= 1) ss += __shfl_xor(ss, off);
  const float rms = rsqrtf(ss * (1.0f / 128.0f) + 1e-6f);
  const float* w = isq ? qw : kw;
  const float2 w2 = *(const float2*)(w + 2 * l);
  const float n0 = v0 * rms * w2.x, n1 = v1 * rms * w2.y;
  const float sx0 = __shfl_xor(n0, 32), sx1 = __shfl_xor(n1, 32);
  const float p0 = (l < 32) ? -sx0 : sx0;
  const float p1 = (l < 32) ? -sx1 : sx1;
  const float2 c2 = *(const float2*)(cosb + (size_t)bt * 128 + 2 * l);
  const float2 s2 = *(const float2*)(sinb + (size_t)bt * 128 + 2 * l);
  const float qsc = isq ? 0.08838834764831845f : 1.0f;  // 1/sqrt(128) folded into Q
  ushort2 o;
  o.x = f2bf((n0 * c2.x + p0 * s2.x) * qsc);
  o.y = f2bf((n1 * c2.y + p1 * s2.y) * qsc);
  const int b = bt >> 11, t = bt & 2047;
  if (isq)
    *(ushort2*)(Qb + (((size_t)(b * 16 + hh) * 2048 + t) << 7) + 2 * l) = o;
  else
    *(ushort2*)(Kb + (((size_t)(b * 4 + (hh - 16)) * 2048 + t) << 7) + 2 * l) = o;
}

// ---------------------------------------------------------------------------
// V transpose+cast: qkv v-columns (B,T,KH,D) -> Vt (B,KH,D,T) bf16
__global__ __launch_bounds__(256)
void v_trans(const unsigned short* __restrict__ qkv, unsigned short* __restrict__ Vt) {
  __shared__ unsigned short tile[64][66];
  const int b = blockIdx.x >> 2, h = blockIdx.x & 3;
  const int t0 = blockIdx.y << 6, d0 = blockIdx.z << 6;
  const int tid = threadIdx.x;
  #pragma unroll
  for (int p = 0; p < 16; ++p) {
    const int id = (p << 8) + tid;
    const int r = id >> 6, c = id & 63;  // r = t, c = d
    tile[r][c] = qkv[(size_t)(b * 2048 + t0 + r) * 3072 + 2560 + (h << 7) + d0 + c];
  }
  __syncthreads();
  #pragma unroll
  for (int p = 0; p < 16; ++p) {
    const int id = (p << 8) + tid;
    const int r = id >> 6, c = id & 63;  // r = d, c = t
    Vt[(size_t)((b * 4 + h) * 128 + d0 + r) * 2048 + t0 + c] = tile[c][r];
  }
}

// ---------------------------------------------------------------------------
// Causal GQA flash attention, paired q-tiles, SWAPPED QK^T (S^T = K*Q^T) so
// each lane owns one q-row: softmax is in-lane + 2 shfls; P packed in-reg
// via v_cvt_pk_bf16_f32; PV uses a PERMUTED contraction order so packed P
// words are lane-local (no exchange). Defer-max (THR=8). LDS 32KB.
// NOTE: no min-waves launch bound — R4's (256,4) capped VGPR at 64 and
// spilled the 64-reg accumulator to scratch (373MB writes/dispatch).
__global__ __launch_bounds__(256)
void attn_fwd(const unsigned short* __restrict__ Qb,  // (B,H,T,D), pre-scaled
              const unsigned short* __restrict__ Kb,  // (B,KH,T,D)
              const unsigned short* __restrict__ Vt,  // (B,KH,D,T)
              unsigned short* __restrict__ Y) {       // (B,T,H,D)
  __shared__ unsigned short Ks[64 * 128];   // 16KB, rows 256B, XOR-swizzled
  __shared__ unsigned short Vs[128 * 64];   // 16KB, rows 128B, XOR-swizzled
  const int bh = blockIdx.x;
  const int b = bh >> 4, h = bh & 15, hk = h >> 2;
  const int p = blockIdx.y;
  const int qtj[2] = {p, 31 - p};
  const int tid = threadIdx.x;
  const int lane = tid & 63, wv = tid >> 6;
  const int lr = lane & 15, lg = lane >> 4;
  const unsigned short* Kp = Kb + (size_t)(b * 4 + hk) * 2048 * 128;
  const unsigned short* Vp = Vt + (size_t)(b * 4 + hk) * 128 * 2048;
  bf16x8 aq[2][4];
  #pragma unroll
  for (int j = 0; j < 2; ++j) {
    const unsigned short* Qp =
        Qb + (size_t)((b * 16 + h) * 2048 + qtj[j] * 64 + wv * 16 + lr) * 128;
    #pragma unroll
    for (int ks = 0; ks < 4; ++ks)
      aq[j][ks] = *(const bf16x8*)(Qp + (ks << 5) + (lg << 3));
  }
  float m_i[2] = {-1e30f, -1e30f};   // per-lane: one q-row per lane
  float l_i[2] = {0.f, 0.f};
  f32x4 acc[2][8] = {};
  const int kr_in = (lane >> 4), kcb = (lane & 15) << 4;   // K chunk: 4 rows x 256B
  const int vr_in = (lane >> 3), vcb = (lane & 7) << 4;    // V chunk: 8 rows x 128B
  const int swb = (lr & 7) << 4;   // row&7 == lr&7 for all fragment rows used
  const int nkb = 32 - p;
  for (int kb = 0; kb < nkb; ++kb) {
    const int k0 = kb << 6;
    #pragma unroll
    for (int i = 0; i < 4; ++i) {
      const int c = (wv << 2) + i;
      { const int r = (c << 2) + kr_in;
        const int sw = kcb ^ ((r & 7) << 4);
        gl_lds16(Kp + (size_t)(k0 + r) * 128 + (sw >> 1), &Ks[c << 9]); }
      { const int r = (c << 3) + vr_in;
        const int sw = vcb ^ ((r & 7) << 4);
        gl_lds16(Vp + (size_t)r * 2048 + k0 + (sw >> 1), &Vs[c << 9]); }
    }
    __syncthreads();
    #pragma unroll
    for (int j = 0; j < 2; ++j) {
      if (kb > qtj[j]) continue;   // uniform; only j=0 can skip
      // S^T = K Q^T: lane holds S[q=lr][kv = 16nf + 4lg + reg]
      f32x4 s[4] = {};
      __builtin_amdgcn_s_setprio(1);
      #pragma unroll
      for (int nf = 0; nf < 4; ++nf) {
        const int row = (nf << 4) + lr;
        #pragma unroll
        for (int ks = 0; ks < 4; ++ks) {
          const bf16x8 bk = *(const bf16x8*)(
              (const char*)Ks + (row << 8) + (((ks << 6) + (lg << 4)) ^ swb));
          s[nf] = __builtin_amdgcn_mfma_f32_16x16x32_bf16(bk, aq[j][ks], s[nf], 0, 0, 0);
        }
      }
      __builtin_amdgcn_s_setprio(0);
      const int qrow = qtj[j] * 64 + wv * 16 + lr;
      if (kb == qtj[j]) {   // causal mask, diag block only
        const int base = qrow - k0 - (lg << 2);  // mask if 16nf + r > base
        #pragma unroll
        for (int nf = 0; nf < 4; ++nf)
          #pragma unroll
          for (int r = 0; r < 4; ++r)
            if (16 * nf + r > base) s[nf][r] = -1e30f;
      }
      // row max: in-lane 16 + 2 shfls
      float mx = s[0][0];
      #pragma unroll
      for (int nf = 0; nf < 4; ++nf)
        #pragma unroll
        for (int r = 0; r < 4; ++r) mx = fmaxf(mx, s[nf][r]);
      mx = fmaxf(mx, __shfl_xor(mx, 16));
      mx = fmaxf(mx, __shfl_xor(mx, 32));
      // defer-max (THR=8)
      if (!__all(mx <= m_i[j] + 8.0f)) {
        const float mn = fmaxf(m_i[j], mx);
        const float r = __expf(m_i[j] - mn);
        m_i[j] = mn;
        l_i[j] *= r;
        #pragma unroll
        for (int df = 0; df < 8; ++df) {
          acc[j][df][0] *= r; acc[j][df][1] *= r;
          acc[j][df][2] *= r; acc[j][df][3] *= r;
        }
      }
      // P = exp(S - m), pack to bf16 pairs in-register
      float se = 0.f;
      unsigned pk[8];
      #pragma unroll
      for (int nf = 0; nf < 4; ++nf) {
        const float p0 = __expf(s[nf][0] - m_i[j]);
        const float p1 = __expf(s[nf][1] - m_i[j]);
        const float p2 = __expf(s[nf][2] - m_i[j]);
        const float p3 = __expf(s[nf][3] - m_i[j]);
        se += (p0 + p1) + (p2 + p3);
        pk[nf * 2] = cvtpk_bf16(p0, p1);
        pk[nf * 2 + 1] = cvtpk_bf16(p2, p3);
      }
      se += __shfl_xor(se, 16);
      se += __shfl_xor(se, 32);
      l_i[j] += se;
      // PV with permuted contraction: K-block c contracts
      // kv = 32c + 4lg + r (j=0..3) and 32c + 16 + 4lg + r (j=4..7)
      union { unsigned u[4]; bf16x8 v; } pb0, pb1;
      pb0.u[0] = pk[0]; pb0.u[1] = pk[1]; pb0.u[2] = pk[2]; pb0.u[3] = pk[3];
      pb1.u[0] = pk[4]; pb1.u[1] = pk[5]; pb1.u[2] = pk[6]; pb1.u[3] = pk[7];
      __builtin_amdgcn_s_setprio(1);
      #pragma unroll
      for (int df = 0; df < 8; ++df) {
        const char* vrow = (const char*)Vs + (((df << 4) + lr) << 7);
        union { bf16x4 h[2]; bf16x8 v; } va;
        va.h[0] = *(const bf16x4*)(vrow + (((lg << 3)) ^ swb));
        va.h[1] = *(const bf16x4*)(vrow + ((32 + (lg << 3)) ^ swb));
        acc[j][df] = __builtin_amdgcn_mfma_f32_16x16x32_bf16(va.v, pb0.v, acc[j][df], 0, 0, 0);
        va.h[0] = *(const bf16x4*)(vrow + ((64 + (lg << 3)) ^ swb));
        va.h[1] = *(const bf16x4*)(vrow + ((96 + (lg << 3)) ^ swb));
        acc[j][df] = __builtin_amdgcn_mfma_f32_16x16x32_bf16(va.v, pb1.v, acc[j][df], 0, 0, 0);
      }
      __builtin_amdgcn_s_setprio(0);
    }
    __syncthreads();
  }
  // epilogue: O^T layout -> lane has q=lr, d = 16df + 4lg + reg
  #pragma unroll
  for (int j = 0; j < 2; ++j) {
    const float inv = 1.0f / l_i[j];
    const int t = qtj[j] * 64 + wv * 16 + lr;
    unsigned short* Yp = Y + (((size_t)b * 2048 + t) * 16 + h) * 128 + (lg << 2);
    #pragma unroll
    for (int df = 0; df < 8; ++df) {
      ushort4 o;
      o.x = f2bf(acc[j][df][0] * inv);
      o.y = f2bf(acc[j][df][1] * inv);
      o.z = f2bf(acc[j][df][2] * inv);
      o.w = f2bf(acc[j][df][3] * inv);
      *(ushort4*)(Yp + (df << 4)) = o;
    }
  }
}

// ---------------------------------------------------------------------------
extern "C" void kernel_launch(void* const* d_in, const int* in_sizes, int n_in,
                              void* d_out, int out_size, void* d_ws, size_t ws_size,
                              hipStream_t stream) {
  const float* x    = (const float*)d_in[0];
  const float* cosb = (const float*)d_in[1];
  const float* sinb = (const float*)d_in[2];
  const float* Wq   = (const float*)d_in[3];
  const float* Wk   = (const float*)d_in[4];
  const float* Wv   = (const float*)d_in[5];
  const float* Wo   = (const float*)d_in[6];
  const float* qw   = (const float*)d_in[7];
  const float* kw   = (const float*)d_in[8];
  char* ws = (char*)d_ws;
  unsigned short* xb   = (unsigned short*)(ws);                       // 16MB x bf16, later reused as Y
  unsigned short* Wcat = (unsigned short*)(ws + (16ull << 20));       // 12MB [Wq;Wk;Wv] bf16
  unsigned short* Wob  = (unsigned short*)(ws + (28ull << 20));       // 8MB Wo bf16
  unsigned short* qkv  = (unsigned short*)(ws + (36ull << 20));       // 24MB (4096,3072) bf16
  unsigned short* Qb   = (unsigned short*)(ws + (60ull << 20));       // 16MB (B,H,T,D)
  unsigned short* Kb   = (unsigned short*)(ws + (76ull << 20));       // 4MB  (B,KH,T,D)
  unsigned short* Vt   = (unsigned short*)(ws + (80ull << 20));       // 4MB  (B,KH,D,T)

  cvt_f32_bf16<<<2048, 256, 0, stream>>>(x, xb, (long)(4096 * 2048 / 4));
  cvt_w3<<<1536, 256, 0, stream>>>(Wq, Wk, Wv, Wcat);
  cvt_f32_bf16<<<2048, 256, 0, stream>>>(Wo, Wob, (long)(2048 * 2048 / 4));

  // qkv = x @ [Wq;Wk;Wv]^T   (M=4096, N=3072, K=2048): 16x12 = 192 blocks
  gemm256<1><<<192, 512, 0, stream>>>(xb, Wcat, qkv, 4096, 3072, 2048);
  // RMSNorm + RoPE -> head-major Q (pre-scaled), K
  norm_rope<<<2 * 2048 * 20 / 4, 256, 0, stream>>>(qkv, cosb, sinb, qw, kw, Qb, Kb);
  // V -> transposed bf16
  v_trans<<<dim3(8, 32, 2), 256, 0, stream>>>(qkv, Vt);
  // attention -> Y (reuses xb); paired q-tiles
  attn_fwd<<<dim3(32, 16), 256, 0, stream>>>(Qb, Kb, Vt, xb);
  // out = Y @ Wo^T  (M=4096, N=2048, K=2048): 16x8 = 128 blocks, fp32 out
  gemm256<0><<<128, 512, 0, stream>>>(xb, Wob, d_out, 4096, 2048, 2048);
}